// Round 15
// baseline (118.559 us; speedup 1.0000x reference)
//
#include <hip/hip_runtime.h>
#include <hip/hip_bf16.h>

#define BQ 4
#define SQ 4096
#define DQ 256
#define N3 768
#define KBLK 64
#define NITER (SQ / KBLK)
#define KHALF (NITER / 2)
#define LOG2E 1.44269504f
#define THR2 11.5415603f  // 8 * log2(e)

typedef __attribute__((ext_vector_type(8))) _Float16 f16x8;
typedef __attribute__((ext_vector_type(4))) float f32x4;
typedef __attribute__((ext_vector_type(4))) unsigned int u32x4;

__device__ __forceinline__ short f2h(float f) {
  _Float16 h = (_Float16)f;
  union { _Float16 h; short s; } v; v.h = h;
  return v.s;
}

__device__ __forceinline__ void gload16(const void* g, void* lds) {
  __builtin_amdgcn_global_load_lds(
      (const __attribute__((address_space(1))) unsigned int*)g,
      (__attribute__((address_space(3))) unsigned int*)lds, 16, 0, 0);
}

// ---------------- Wcomb = Wproj @ Wfc ; c0 = bproj @ Wfc + bfc ----------------
__global__ void wcomb_kernel(const float* __restrict__ Wproj,
                             const float* __restrict__ bproj,
                             const float* __restrict__ Wfc,
                             const float* __restrict__ bfc,
                             float* __restrict__ Wc) {
  __shared__ float wf[256];
  const int t = threadIdx.x;
  wf[t] = Wfc[t];
  __syncthreads();
  float acc = 0.f;
  for (int j = 0; j < 256; ++j) acc += Wproj[(size_t)t * 256 + j] * wf[j];
  Wc[t] = acc;
  if (t == 0) {
    float c = bfc[0];
    for (int j = 0; j < 256; ++j) c += bproj[j] * wf[j];
    Wc[256] = c;
  }
}

// ---------------- W16T[n][k] = fp16(Wqkv[k][n]), coalesced via LDS ----------
__global__ void wconv_kernel(const float* __restrict__ Wqkv,
                             short* __restrict__ W16T) {
  __shared__ float tile[64][65];
  const int nb = blockIdx.x * 64;  // 12
  const int kb = blockIdx.y * 64;  // 4
  const int t = threadIdx.x;
  const int tr = t >> 6, tc = t & 63;
#pragma unroll
  for (int i = 0; i < 16; ++i)
    tile[tr + i * 4][tc] = Wqkv[(size_t)(kb + tr + i * 4) * N3 + nb + tc];
  __syncthreads();
#pragma unroll
  for (int i = 0; i < 16; ++i)
    W16T[(size_t)(nb + tr + i * 4) * 256 + kb + tc] = f2h(tile[tc][tr + i * 4]);
}

// ---------------- QKV projection: counted-vmcnt pipelined ----------------
// K columns are pre-scaled by log2(e) so attention can use native exp2.
__global__ __launch_bounds__(1024, 4) void qkv_kernel(
    const float* __restrict__ x, const short* __restrict__ W16T,
    const float* __restrict__ bqkv, const float* __restrict__ Wc,
    short* __restrict__ Qb, short* __restrict__ Kb, float* __restrict__ u) {
  __shared__ short xs[64][264];       // [m][k] fp16, pitch 528B
  __shared__ short ws[2][64][256];    // [buf][n][k], XOR-swizzled chunks
  __shared__ float u_red[4][4][16];
  const int t = threadIdx.x;
  const int l = t & 63, w = t >> 6;
  const int lr = l & 15, lg = l >> 4;
  const int mq = w >> 2, nq = w & 3;
  const int Mbase = blockIdx.x * 64;

#define STAGE_W(BUF, NT)                                                      \
  {                                                                           \
    _Pragma("unroll") for (int i = 0; i < 2; ++i) {                           \
      const int n = w * 4 + i * 2 + (l >> 5);                                 \
      const int gc = (l & 31) ^ (n & 7);                                      \
      gload16(W16T + (size_t)((NT)*64 + n) * 256 + gc * 8,                    \
              &ws[BUF][w * 4 + i * 2][0]);                                    \
    }                                                                         \
  }

  STAGE_W(0, 0);

  // stage x tile (plain LDS writes)
  {
    const int m = t >> 4, kc = (t & 15) * 16;
    const float* src = x + (size_t)(Mbase + m) * DQ + kc;
    short tmp[16];
#pragma unroll
    for (int i = 0; i < 16; ++i) tmp[i] = f2h(src[i]);
    *(u32x4*)&xs[m][kc] = *(u32x4*)&tmp[0];
    *(u32x4*)&xs[m][kc + 8] = *(u32x4*)&tmp[8];
  }

  // preload all bias/Wc values (keeps in-loop VM queue = staging only)
  float bias_qk[8], bias_u[4], wc_u[4];
#pragma unroll
  for (int i = 0; i < 8; ++i) bias_qk[i] = bqkv[i * 64 + nq * 16 + lr];
#pragma unroll
  for (int i = 0; i < 4; ++i) {
    bias_u[i] = bqkv[512 + i * 64 + nq * 16 + lr];
    wc_u[i] = Wc[i * 64 + nq * 16 + lr];
  }

  __syncthreads();  // drains prologue (ws buf0 + xs + preloads)

  unsigned qksto[8][2];
  float upart[4] = {0.f, 0.f, 0.f, 0.f};

#pragma unroll
  for (int nt = 0; nt < 12; ++nt) {
    const int cur = nt & 1;
    if (nt + 1 < 12) {
      STAGE_W(cur ^ 1, nt + 1);
      asm volatile("s_waitcnt vmcnt(2)" ::: "memory");
    } else {
      asm volatile("s_waitcnt vmcnt(0)" ::: "memory");
    }
    __builtin_amdgcn_s_barrier();
    __builtin_amdgcn_sched_barrier(0);

    f32x4 acc = {};
    const char* wR = (const char*)&ws[cur][nq * 16 + lr][0];
#pragma unroll
    for (int kk = 0; kk < 8; ++kk) {
      f16x8 af = *(f16x8*)&xs[mq * 16 + lr][kk * 32 + lg * 8];
      f16x8 bfr = *(const f16x8*)(wR + (((4 * kk + lg) ^ (lr & 7)) << 4));
      acc = __builtin_amdgcn_mfma_f32_16x16x32_f16(af, bfr, acc, 0, 0, 0);
    }
    if (nt < 8) {
      const float sc = (nt < 4) ? 1.f : LOG2E;  // K pre-scaled for exp2
      unsigned s0 = (unsigned short)f2h((acc[0] + bias_qk[nt]) * sc);
      unsigned s1 = (unsigned short)f2h((acc[1] + bias_qk[nt]) * sc);
      unsigned s2 = (unsigned short)f2h((acc[2] + bias_qk[nt]) * sc);
      unsigned s3 = (unsigned short)f2h((acc[3] + bias_qk[nt]) * sc);
      qksto[nt][0] = s0 | (s1 << 16);
      qksto[nt][1] = s2 | (s3 << 16);
    } else {
#pragma unroll
      for (int r = 0; r < 4; ++r) upart[r] += (acc[r] + bias_u[nt - 8]) * wc_u[nt - 8];
    }
    __builtin_amdgcn_s_barrier();
  }

  // epilogue: Q/K stores
#pragma unroll
  for (int nt = 0; nt < 8; ++nt) {
    const int col = nt * 64 + nq * 16 + lr;
#pragma unroll
    for (int r = 0; r < 4; ++r) {
      const int row = Mbase + mq * 16 + lg * 4 + r;
      const short sv = (short)((qksto[nt][r >> 1] >> ((r & 1) * 16)) & 0xFFFF);
      if (col < 256) Qb[(size_t)row * DQ + col] = sv;
      else           Kb[(size_t)row * DQ + (col - 256)] = sv;
    }
  }

  // u reduction
#pragma unroll
  for (int mask = 1; mask <= 8; mask <<= 1)
#pragma unroll
    for (int r = 0; r < 4; ++r) upart[r] += __shfl_xor(upart[r], mask, 64);
  if (lr == 0) {
#pragma unroll
    for (int r = 0; r < 4; ++r) u_red[mq][nq][lg * 4 + r] = upart[r];
  }
  __syncthreads();
  if (t < 64)
    u[Mbase + t] = u_red[t >> 4][0][t & 15] + u_red[t >> 4][1][t & 15] +
                   u_red[t >> 4][2][t & 15] + u_red[t >> 4][3][t & 15];
#undef STAGE_W
}

// ---------------- Flash attention: BARRIER-FREE main loop ----------------
// grid 512, 512 thr = 8 waves = 2 qg x 4 key-quarters (1 block/CU, 139KB LDS).
// Each wave stages ITS OWN 16 key-rows per tile into a wave-PRIVATE
// double-buffered LDS region (global_load_lds) and reads only those.
// -> no cross-wave dependency in the loop: no s_barrier, no syncthreads;
// only per-wave vmcnt(8). Waves fully self-pace (no lockstep).
__global__ __launch_bounds__(512, 2) void attn_kernel(
    const short* __restrict__ Qb, const short* __restrict__ Kb,
    const float* __restrict__ u, float* __restrict__ Pm,
    float* __restrict__ Pd, float* __restrict__ Pn) {
  __shared__ short Kw[8][2][16][256];  // per-wave private [w][buf][row][d]
  __shared__ __align__(16) float u_lds[2048];
  __shared__ float Mrg[2][4][32][3];   // [qg][h][row]{m,den,num}

  const int t = threadIdx.x;
  const int l = t & 63, w = t >> 6;
  const int lr = l & 15, lg = l >> 4;
  const int qg = w >> 2, h = w & 3;
  const int bid = blockIdx.x;
  const int b = bid & 3;
  const int half = (bid >> 2) & 1;     // bid%8 -> XCD: one (b,half) per XCD
  const int qbase = (bid >> 3) * 64;

  const short* kbase = Kb + ((size_t)b * SQ + (size_t)half * (SQ / 2) + h * 16) * DQ;
  const float* ubase = u + (size_t)b * SQ + half * (SQ / 2);
  short* kw = &Kw[w][0][0][0];         // wave-private base (2 bufs x 4096 shorts)

  // stage tile KB's 16 rows for quarter h into private buf (8 x gload16)
#define STAGE(BUF, KB)                                                      \
  {                                                                         \
    _Pragma("unroll") for (int i = 0; i < 8; ++i) {                         \
      const int lrow = i * 2 + (l >> 5);                                    \
      const int gc = (l & 31) ^ (lrow & 7);                                 \
      gload16(kbase + (size_t)(KB) * (64 * DQ) + (size_t)lrow * DQ + gc * 8, \
              kw + (BUF)*4096 + i * 512);                                   \
    }                                                                       \
  }

  STAGE(0, 0);
  // stage u slice (2048 f32): wave w covers floats w*256..+255, per-lane src
  gload16(ubase + w * 256 + (l << 2), &u_lds[w * 256]);

  // Q fragments (B-operand): wave's 32 q-rows (qg), qrow = mm*16+lr
  f16x8 qf[2][8];
#pragma unroll
  for (int mm = 0; mm < 2; ++mm) {
    const short* qptr = Qb + (size_t)(b * SQ + qbase + qg * 32 + mm * 16 + lr) * DQ;
#pragma unroll
    for (int kk = 0; kk < 8; ++kk)
      qf[mm][kk] = *(const f16x8*)(qptr + kk * 32 + lg * 8);
  }

  // hoist loop-invariant ds_read offsets (XOR swizzle keyed on local row)
  int koff[8];
#pragma unroll
  for (int kk = 0; kk < 8; ++kk) koff[kk] = ((4 * kk + lg) ^ (lr & 7)) << 4;
  const char* kR0 = (const char*)(kw + lr * 256);  // + cur*8192 bytes per buf

  float m_run[2] = {-1e30f, -1e30f};
  float num[2] = {0.f, 0.f}, den[2] = {0.f, 0.f};

  __syncthreads();  // ONE-TIME drain: buf0 + u_lds + qf ready; queue clean

  for (int kb = 0; kb < KHALF; ++kb) {
    const int cur = kb & 1;
    if (kb + 1 < KHALF) {
      STAGE(cur ^ 1, kb + 1);
      asm volatile("s_waitcnt vmcnt(8)" ::: "memory");  // own tile-kb done
    } else {
      asm volatile("s_waitcnt vmcnt(0)" ::: "memory");
    }
    __builtin_amdgcn_sched_barrier(0);   // no s_barrier: wave-private buffer

    // S^T = K Q^T: 16 keys x 32 q (2 independent 8-deep chains)
    const char* kR = kR0 + cur * 8192;
    f32x4 s[2] = {};
    __builtin_amdgcn_s_setprio(1);
#pragma unroll
    for (int kk = 0; kk < 8; ++kk) {
      f16x8 kf = *(const f16x8*)(kR + koff[kk]);
      s[0] = __builtin_amdgcn_mfma_f32_16x16x32_f16(kf, qf[0][kk], s[0], 0, 0, 0);
      s[1] = __builtin_amdgcn_mfma_f32_16x16x32_f16(kf, qf[1][kk], s[1], 0, 0, 0);
    }
    __builtin_amdgcn_s_setprio(0);

    // defer-max online softmax (base 2); zero cross-lane ops in common path
    bool over = false;
#pragma unroll
    for (int mm = 0; mm < 2; ++mm)
#pragma unroll
      for (int r = 0; r < 4; ++r) over = over || (s[mm][r] > m_run[mm] + THR2);
    if (__any(over)) {
#pragma unroll
      for (int mm = 0; mm < 2; ++mm) {
        float mt = fmaxf(fmaxf(s[mm][0], s[mm][1]), fmaxf(s[mm][2], s[mm][3]));
        mt = fmaxf(mt, __shfl_xor(mt, 16, 64));
        mt = fmaxf(mt, __shfl_xor(mt, 32, 64));
        const float mn = fmaxf(m_run[mm], mt);
        const float sc = exp2f(m_run[mm] - mn);
        m_run[mm] = mn;
        num[mm] *= sc;
        den[mm] *= sc;
      }
    }
    {
      const f32x4 uv = *(const f32x4*)&u_lds[kb * 64 + h * 16 + lg * 4];
#pragma unroll
      for (int mm = 0; mm < 2; ++mm)
#pragma unroll
        for (int r = 0; r < 4; ++r) {
          const float p = exp2f(s[mm][r] - m_run[mm]);  // <= 2^11.54 = e^8
          den[mm] += p;
          num[mm] += p * uv[r];
        }
    }
    // no barrier: next STAGE overwrites only this wave's own finished buffer
  }

  // reduce per-lane partials over the lg axis (keys)
#pragma unroll
  for (int mm = 0; mm < 2; ++mm) {
    num[mm] += __shfl_xor(num[mm], 16, 64);
    num[mm] += __shfl_xor(num[mm], 32, 64);
    den[mm] += __shfl_xor(den[mm], 16, 64);
    den[mm] += __shfl_xor(den[mm], 32, 64);
  }
  if (lg == 0) {
#pragma unroll
    for (int mm = 0; mm < 2; ++mm) {
      Mrg[qg][h][mm * 16 + lr][0] = m_run[mm];
      Mrg[qg][h][mm * 16 + lr][1] = den[mm];
      Mrg[qg][h][mm * 16 + lr][2] = num[mm];
    }
  }
  __syncthreads();

  if (t < 64) {
    const int row = t & 31, qg2 = t >> 5;
    float M = Mrg[qg2][0][row][0];
#pragma unroll
    for (int hh = 1; hh < 4; ++hh) M = fmaxf(M, Mrg[qg2][hh][row][0]);
    float dt = 0.f, nt = 0.f;
#pragma unroll
    for (int hh = 0; hh < 4; ++hh) {
      const float e = exp2f(Mrg[qg2][hh][row][0] - M);
      dt += e * Mrg[qg2][hh][row][1];
      nt += e * Mrg[qg2][hh][row][2];
    }
    const size_t idx = (size_t)half * (BQ * SQ) + (size_t)b * SQ + qbase + row +
                       qg2 * 32;
    Pm[idx] = M; Pd[idx] = dt; Pn[idx] = nt;
  }
#undef STAGE
}

// ---------------- merge the 2 key-halves ----------------
__global__ void merge_kernel(const float* __restrict__ Pm,
                             const float* __restrict__ Pd,
                             const float* __restrict__ Pn,
                             const float* __restrict__ Wc,
                             float* __restrict__ out) {
  const int gid = blockIdx.x * 256 + threadIdx.x;
  const float m0 = Pm[gid], m1 = Pm[BQ * SQ + gid];
  const float M = fmaxf(m0, m1);
  const float e0 = exp2f(m0 - M), e1 = exp2f(m1 - M);
  const float den = e0 * Pd[gid] + e1 * Pd[BQ * SQ + gid];
  const float num = e0 * Pn[gid] + e1 * Pn[BQ * SQ + gid];
  out[gid] = num / den + Wc[256];
}

// ---------------- launch ----------------
extern "C" void kernel_launch(void* const* d_in, const int* in_sizes, int n_in,
                              void* d_out, int out_size, void* d_ws, size_t ws_size,
                              hipStream_t stream) {
  const float* x     = (const float*)d_in[0];
  const float* Wqkv  = (const float*)d_in[1];
  const float* bqkv  = (const float*)d_in[2];
  const float* Wproj = (const float*)d_in[3];
  const float* bproj = (const float*)d_in[4];
  const float* Wfc   = (const float*)d_in[5];
  const float* bfc   = (const float*)d_in[6];
  float* out = (float*)d_out;

  const size_t SEG = (size_t)BQ * SQ * DQ * 2;  // 8 MB per fp16 tensor
  char* wsb = (char*)d_ws;
  short* Qb   = (short*)(wsb);
  short* Kb   = (short*)(wsb + SEG);
  char* base  = wsb + 2 * SEG;
  float* Wc   = (float*)(base);                          // 257 f
  float* u    = (float*)(base + 4096);                   // 16384 f
  short* W16T = (short*)(base + 4096 + 65536);           // 384 KB
  float* Pm   = (float*)(base + 4096 + 65536 + 393216);  // 32768 f
  float* Pd   = Pm + 2 * BQ * SQ;
  float* Pn   = Pd + 2 * BQ * SQ;

  wcomb_kernel<<<1, 256, 0, stream>>>(Wproj, bproj, Wfc, bfc, Wc);
  wconv_kernel<<<dim3(12, 4), 256, 0, stream>>>(Wqkv, W16T);
  qkv_kernel<<<256, 1024, 0, stream>>>(x, W16T, bqkv, Wc, Qb, Kb, u);
  attn_kernel<<<512, 512, 0, stream>>>(Qb, Kb, u, Pm, Pd, Pn);
  merge_kernel<<<BQ * SQ / 256, 256, 0, stream>>>(Pm, Pd, Pn, Wc, out);
}

// Round 16
// 93.781 us; speedup vs baseline: 1.2642x; 1.2642x over previous
//
#include <hip/hip_runtime.h>
#include <hip/hip_bf16.h>

#define BQ 4
#define SQ 4096
#define DQ 256
#define N3 768
#define KBLK 64
#define NITER (SQ / KBLK)
#define KHALF (NITER / 2)
#define LOG2E 1.44269504f
#define THR2 11.5415603f  // 8 * log2(e)

typedef __attribute__((ext_vector_type(8))) _Float16 f16x8;
typedef __attribute__((ext_vector_type(4))) float f32x4;
typedef __attribute__((ext_vector_type(4))) unsigned int u32x4;

__device__ __forceinline__ short f2h(float f) {
  _Float16 h = (_Float16)f;
  union { _Float16 h; short s; } v; v.h = h;
  return v.s;
}

__device__ __forceinline__ void gload16(const void* g, void* lds) {
  __builtin_amdgcn_global_load_lds(
      (const __attribute__((address_space(1))) unsigned int*)g,
      (__attribute__((address_space(3))) unsigned int*)lds, 16, 0, 0);
}

// ---- prep: blocks 0..47 transpose/convert Wqkv -> W16T; block 48 = Wcomb ----
__global__ __launch_bounds__(256) void prep_kernel(
    const float* __restrict__ Wqkv, const float* __restrict__ Wproj,
    const float* __restrict__ bproj, const float* __restrict__ Wfc,
    const float* __restrict__ bfc, short* __restrict__ W16T,
    float* __restrict__ Wc) {
  const int t = threadIdx.x;
  if (blockIdx.x == 48) {
    __shared__ float wf[256];
    wf[t] = Wfc[t];
    __syncthreads();
    float acc = 0.f;
    for (int j = 0; j < 256; ++j) acc += Wproj[(size_t)t * 256 + j] * wf[j];
    Wc[t] = acc;
    if (t == 0) {
      float c = bfc[0];
      for (int j = 0; j < 256; ++j) c += bproj[j] * wf[j];
      Wc[256] = c;
    }
    return;
  }
  __shared__ float tile[64][65];
  const int nb = (blockIdx.x % 12) * 64;
  const int kb = (blockIdx.x / 12) * 64;
  const int tr = t >> 6, tc = t & 63;
#pragma unroll
  for (int i = 0; i < 16; ++i)
    tile[tr + i * 4][tc] = Wqkv[(size_t)(kb + tr + i * 4) * N3 + nb + tc];
  __syncthreads();
#pragma unroll
  for (int i = 0; i < 16; ++i)
    W16T[(size_t)(nb + tr + i * 4) * 256 + kb + tc] = f2h(tile[tc][tr + i * 4]);
}

// ---------------- QKV projection: counted-vmcnt pipelined ----------------
// K columns are pre-scaled by log2(e) so attention can use native exp2.
__global__ __launch_bounds__(1024, 4) void qkv_kernel(
    const float* __restrict__ x, const short* __restrict__ W16T,
    const float* __restrict__ bqkv, const float* __restrict__ Wc,
    short* __restrict__ Qb, short* __restrict__ Kb, float* __restrict__ u) {
  __shared__ short xs[64][264];       // [m][k] fp16, pitch 528B
  __shared__ short ws[2][64][256];    // [buf][n][k], XOR-swizzled chunks
  __shared__ float u_red[4][4][16];
  const int t = threadIdx.x;
  const int l = t & 63, w = t >> 6;
  const int lr = l & 15, lg = l >> 4;
  const int mq = w >> 2, nq = w & 3;
  const int Mbase = blockIdx.x * 64;

#define STAGE_W(BUF, NT)                                                      \
  {                                                                           \
    _Pragma("unroll") for (int i = 0; i < 2; ++i) {                           \
      const int n = w * 4 + i * 2 + (l >> 5);                                 \
      const int gc = (l & 31) ^ (n & 7);                                      \
      gload16(W16T + (size_t)((NT)*64 + n) * 256 + gc * 8,                    \
              &ws[BUF][w * 4 + i * 2][0]);                                    \
    }                                                                         \
  }

  STAGE_W(0, 0);

  // stage x tile (plain LDS writes)
  {
    const int m = t >> 4, kc = (t & 15) * 16;
    const float* src = x + (size_t)(Mbase + m) * DQ + kc;
    short tmp[16];
#pragma unroll
    for (int i = 0; i < 16; ++i) tmp[i] = f2h(src[i]);
    *(u32x4*)&xs[m][kc] = *(u32x4*)&tmp[0];
    *(u32x4*)&xs[m][kc + 8] = *(u32x4*)&tmp[8];
  }

  // preload all bias/Wc values (keeps in-loop VM queue = staging only)
  float bias_qk[8], bias_u[4], wc_u[4];
#pragma unroll
  for (int i = 0; i < 8; ++i) bias_qk[i] = bqkv[i * 64 + nq * 16 + lr];
#pragma unroll
  for (int i = 0; i < 4; ++i) {
    bias_u[i] = bqkv[512 + i * 64 + nq * 16 + lr];
    wc_u[i] = Wc[i * 64 + nq * 16 + lr];
  }

  __syncthreads();  // drains prologue (ws buf0 + xs + preloads)

  unsigned qksto[8][2];
  float upart[4] = {0.f, 0.f, 0.f, 0.f};

#pragma unroll
  for (int nt = 0; nt < 12; ++nt) {
    const int cur = nt & 1;
    if (nt + 1 < 12) {
      STAGE_W(cur ^ 1, nt + 1);
      asm volatile("s_waitcnt vmcnt(2)" ::: "memory");
    } else {
      asm volatile("s_waitcnt vmcnt(0)" ::: "memory");
    }
    __builtin_amdgcn_s_barrier();
    __builtin_amdgcn_sched_barrier(0);

    f32x4 acc = {};
    const char* wR = (const char*)&ws[cur][nq * 16 + lr][0];
#pragma unroll
    for (int kk = 0; kk < 8; ++kk) {
      f16x8 af = *(f16x8*)&xs[mq * 16 + lr][kk * 32 + lg * 8];
      f16x8 bfr = *(const f16x8*)(wR + (((4 * kk + lg) ^ (lr & 7)) << 4));
      acc = __builtin_amdgcn_mfma_f32_16x16x32_f16(af, bfr, acc, 0, 0, 0);
    }
    if (nt < 8) {
      const float sc = (nt < 4) ? 1.f : LOG2E;  // K pre-scaled for exp2
      unsigned s0 = (unsigned short)f2h((acc[0] + bias_qk[nt]) * sc);
      unsigned s1 = (unsigned short)f2h((acc[1] + bias_qk[nt]) * sc);
      unsigned s2 = (unsigned short)f2h((acc[2] + bias_qk[nt]) * sc);
      unsigned s3 = (unsigned short)f2h((acc[3] + bias_qk[nt]) * sc);
      qksto[nt][0] = s0 | (s1 << 16);
      qksto[nt][1] = s2 | (s3 << 16);
    } else {
#pragma unroll
      for (int r = 0; r < 4; ++r) upart[r] += (acc[r] + bias_u[nt - 8]) * wc_u[nt - 8];
    }
    __builtin_amdgcn_s_barrier();
  }

  // epilogue: Q/K stores
#pragma unroll
  for (int nt = 0; nt < 8; ++nt) {
    const int col = nt * 64 + nq * 16 + lr;
#pragma unroll
    for (int r = 0; r < 4; ++r) {
      const int row = Mbase + mq * 16 + lg * 4 + r;
      const short sv = (short)((qksto[nt][r >> 1] >> ((r & 1) * 16)) & 0xFFFF);
      if (col < 256) Qb[(size_t)row * DQ + col] = sv;
      else           Kb[(size_t)row * DQ + (col - 256)] = sv;
    }
  }

  // u reduction
#pragma unroll
  for (int mask = 1; mask <= 8; mask <<= 1)
#pragma unroll
    for (int r = 0; r < 4; ++r) upart[r] += __shfl_xor(upart[r], mask, 64);
  if (lr == 0) {
#pragma unroll
    for (int r = 0; r < 4; ++r) u_red[mq][nq][lg * 4 + r] = upart[r];
  }
  __syncthreads();
  if (t < 64)
    u[Mbase + t] = u_red[t >> 4][0][t & 15] + u_red[t >> 4][1][t & 15] +
                   u_red[t >> 4][2][t & 15] + u_red[t >> 4][3][t & 15];
#undef STAGE_W
}

// ---------------- Flash attention: r12 structure + VALU diet ----------------
// grid 512 (2 blocks/CU), 256 thr (4 waves = 2 qg x 2 key-halves-of-tile).
// Block = 64 q-rows x 2048 keys (32 iters). Counted vmcnt(8). Softmax:
// native v_exp_f32 (__builtin_amdgcn_exp2f), max-tree gate, hoisted offsets.
__global__ __launch_bounds__(256, 2) void attn_kernel(
    const short* __restrict__ Qb, const short* __restrict__ Kb,
    const float* __restrict__ u, float* __restrict__ Pm,
    float* __restrict__ Pd, float* __restrict__ Pn) {
  __shared__ short Ks[2][64][256];     // [buf][key][d], XOR-swizzled chunks
  __shared__ __align__(16) float u_lds[2048];
  __shared__ float Mrg[2][2][32][3];   // [qg][h][row]{m,den,num}

  const int t = threadIdx.x;
  const int l = t & 63, w = t >> 6;
  const int lr = l & 15, lg = l >> 4;
  const int qg = w >> 1, h = w & 1;
  const int bid = blockIdx.x;
  const int b = bid & 3;
  const int half = (bid >> 2) & 1;     // bid%8 -> XCD: one (b,half) per XCD
  const int qbase = (bid >> 3) * 64;

  const short* kbase = Kb + ((size_t)b * SQ + (size_t)half * (SQ / 2)) * DQ;
  const float* ubase = u + (size_t)b * SQ + half * (SQ / 2);

#define STAGE(BUF, KB)                                                      \
  {                                                                         \
    _Pragma("unroll") for (int i = 0; i < 8; ++i) {                         \
      const int kr = w * 16 + i * 2 + (l >> 5);                             \
      const int gc = (l & 31) ^ (kr & 7);                                   \
      gload16(kbase + (size_t)((KB)*64 + kr) * DQ + gc * 8,                 \
              &Ks[BUF][w * 16 + i * 2][0]);                                 \
    }                                                                       \
  }

  STAGE(0, 0);
  // stage this (b,half)'s u slice (2048 f32): lane l loads floats 4l..4l+3
  gload16(ubase + w * 256 + (l << 2), &u_lds[w * 256]);
  gload16(ubase + (4 + w) * 256 + (l << 2), &u_lds[(4 + w) * 256]);

  // Q fragments (B-operand): wave's 32 q-rows (qg), qrow = mm*16+lr
  f16x8 qf[2][8];
#pragma unroll
  for (int mm = 0; mm < 2; ++mm) {
    const short* qptr = Qb + (size_t)(b * SQ + qbase + qg * 32 + mm * 16 + lr) * DQ;
#pragma unroll
    for (int kk = 0; kk < 8; ++kk)
      qf[mm][kk] = *(const f16x8*)(qptr + kk * 32 + lg * 8);
  }

  // hoist loop-invariant XOR-swizzled fragment offsets
  int koff[8];
#pragma unroll
  for (int kk = 0; kk < 8; ++kk) koff[kk] = ((4 * kk + lg) ^ (lr & 7)) << 4;

  float m_run[2] = {-1e30f, -1e30f};
  float num[2] = {0.f, 0.f}, den[2] = {0.f, 0.f};

  __syncthreads();  // prologue drain: buf0 + u_lds + qf ready

  for (int kb = 0; kb < KHALF; ++kb) {
    const int cur = kb & 1;
    if (kb + 1 < KHALF) {
      STAGE(cur ^ 1, kb + 1);
      asm volatile("s_waitcnt vmcnt(8)" ::: "memory");  // cur-tile loads done
    } else {
      asm volatile("s_waitcnt vmcnt(0)" ::: "memory");
    }
    __builtin_amdgcn_s_barrier();          // whole tile visible; next-tile
    __builtin_amdgcn_sched_barrier(0);     // loads remain in flight

    // S^T = K Q^T on this wave's 32 keys (4 independent 8-deep chains)
    f32x4 s[2][2] = {};
    __builtin_amdgcn_s_setprio(1);
#pragma unroll
    for (int kc = 0; kc < 2; ++kc) {
      const char* kR = (const char*)&Ks[cur][h * 32 + kc * 16 + lr][0];
#pragma unroll
      for (int kk = 0; kk < 8; ++kk) {
        f16x8 kf = *(const f16x8*)(kR + koff[kk]);
        s[kc][0] = __builtin_amdgcn_mfma_f32_16x16x32_f16(kf, qf[0][kk], s[kc][0], 0, 0, 0);
        s[kc][1] = __builtin_amdgcn_mfma_f32_16x16x32_f16(kf, qf[1][kk], s[kc][1], 0, 0, 0);
      }
    }
    __builtin_amdgcn_s_setprio(0);

    // max-tree gate (7 fmax per mm), defer-max online softmax (base 2)
    float mx[2];
#pragma unroll
    for (int mm = 0; mm < 2; ++mm)
      mx[mm] = fmaxf(fmaxf(fmaxf(s[0][mm][0], s[0][mm][1]),
                           fmaxf(s[0][mm][2], s[0][mm][3])),
                     fmaxf(fmaxf(s[1][mm][0], s[1][mm][1]),
                           fmaxf(s[1][mm][2], s[1][mm][3])));
    const bool over = (mx[0] > m_run[0] + THR2) || (mx[1] > m_run[1] + THR2);
    if (__any(over)) {
#pragma unroll
      for (int mm = 0; mm < 2; ++mm) {
        float mt = mx[mm];
        mt = fmaxf(mt, __shfl_xor(mt, 16, 64));
        mt = fmaxf(mt, __shfl_xor(mt, 32, 64));
        const float mn = fmaxf(m_run[mm], mt);
        const float sc = __builtin_amdgcn_exp2f(m_run[mm] - mn);
        m_run[mm] = mn;
        num[mm] *= sc;
        den[mm] *= sc;
      }
    }
#pragma unroll
    for (int kc = 0; kc < 2; ++kc) {
      const f32x4 uv = *(const f32x4*)&u_lds[kb * 64 + h * 32 + kc * 16 + lg * 4];
#pragma unroll
      for (int mm = 0; mm < 2; ++mm)
#pragma unroll
        for (int r = 0; r < 4; ++r) {
          const float p = __builtin_amdgcn_exp2f(s[kc][mm][r] - m_run[mm]);
          den[mm] += p;
          num[mm] += p * uv[r];
        }
    }
    __builtin_amdgcn_s_barrier();  // readers done before next STAGE overwrite
  }

  // reduce per-lane partials over the lg axis (keys)
#pragma unroll
  for (int mm = 0; mm < 2; ++mm) {
    num[mm] += __shfl_xor(num[mm], 16, 64);
    num[mm] += __shfl_xor(num[mm], 32, 64);
    den[mm] += __shfl_xor(den[mm], 16, 64);
    den[mm] += __shfl_xor(den[mm], 32, 64);
  }
  if (lg == 0) {
#pragma unroll
    for (int mm = 0; mm < 2; ++mm) {
      Mrg[qg][h][mm * 16 + lr][0] = m_run[mm];
      Mrg[qg][h][mm * 16 + lr][1] = den[mm];
      Mrg[qg][h][mm * 16 + lr][2] = num[mm];
    }
  }
  __syncthreads();

  if (t < 64) {
    const int row = t & 31, qg2 = t >> 5;
    const float m0 = Mrg[qg2][0][row][0], m1 = Mrg[qg2][1][row][0];
    const float M = fmaxf(m0, m1);
    const float e0 = __builtin_amdgcn_exp2f(m0 - M);
    const float e1 = __builtin_amdgcn_exp2f(m1 - M);
    const float dt = e0 * Mrg[qg2][0][row][1] + e1 * Mrg[qg2][1][row][1];
    const float nt = e0 * Mrg[qg2][0][row][2] + e1 * Mrg[qg2][1][row][2];
    const size_t idx = (size_t)half * (BQ * SQ) + (size_t)b * SQ + qbase + qg2 * 32 + row;
    Pm[idx] = M; Pd[idx] = dt; Pn[idx] = nt;
  }
#undef STAGE
}

// ---------------- merge the 2 key-halves ----------------
__global__ void merge_kernel(const float* __restrict__ Pm,
                             const float* __restrict__ Pd,
                             const float* __restrict__ Pn,
                             const float* __restrict__ Wc,
                             float* __restrict__ out) {
  const int gid = blockIdx.x * 256 + threadIdx.x;
  const float m0 = Pm[gid], m1 = Pm[BQ * SQ + gid];
  const float M = fmaxf(m0, m1);
  const float e0 = __builtin_amdgcn_exp2f(m0 - M);
  const float e1 = __builtin_amdgcn_exp2f(m1 - M);
  const float den = e0 * Pd[gid] + e1 * Pd[BQ * SQ + gid];
  const float num = e0 * Pn[gid] + e1 * Pn[BQ * SQ + gid];
  out[gid] = num / den + Wc[256];
}

// ---------------- launch ----------------
extern "C" void kernel_launch(void* const* d_in, const int* in_sizes, int n_in,
                              void* d_out, int out_size, void* d_ws, size_t ws_size,
                              hipStream_t stream) {
  const float* x     = (const float*)d_in[0];
  const float* Wqkv  = (const float*)d_in[1];
  const float* bqkv  = (const float*)d_in[2];
  const float* Wproj = (const float*)d_in[3];
  const float* bproj = (const float*)d_in[4];
  const float* Wfc   = (const float*)d_in[5];
  const float* bfc   = (const float*)d_in[6];
  float* out = (float*)d_out;

  const size_t SEG = (size_t)BQ * SQ * DQ * 2;  // 8 MB per fp16 tensor
  char* wsb = (char*)d_ws;
  short* Qb   = (short*)(wsb);
  short* Kb   = (short*)(wsb + SEG);
  char* base  = wsb + 2 * SEG;
  float* Wc   = (float*)(base);                          // 257 f
  float* u    = (float*)(base + 4096);                   // 16384 f
  short* W16T = (short*)(base + 4096 + 65536);           // 384 KB
  float* Pm   = (float*)(base + 4096 + 65536 + 393216);  // 32768 f
  float* Pd   = Pm + 2 * BQ * SQ;
  float* Pn   = Pd + 2 * BQ * SQ;

  prep_kernel<<<49, 256, 0, stream>>>(Wqkv, Wproj, bproj, Wfc, bfc, W16T, Wc);
  qkv_kernel<<<256, 1024, 0, stream>>>(x, W16T, bqkv, Wc, Qb, Kb, u);
  attn_kernel<<<512, 256, 0, stream>>>(Qb, Kb, u, Pm, Pd, Pn);
  merge_kernel<<<BQ * SQ / 256, 256, 0, stream>>>(Pm, Pd, Pn, Wc, out);
}